// Round 7
// baseline (1733.366 us; speedup 1.0000x reference)
//
#include <hip/hip_runtime.h>

typedef unsigned short u16;
using bf8   = __attribute__((ext_vector_type(8))) short;  // 8 bf16 (4 VGPRs)
using bf4   = __attribute__((ext_vector_type(4))) short;  // 4 bf16
using f32x4 = __attribute__((ext_vector_type(4))) float;

#define B_ 256
#define T_ 512
#define D_ 64
#define H_ 256
#define Tc_ 64
#define NC_ (T_ / Tc_)
#define GEMMB_ 208   // gemm role blocks; 48+208=256 CUs

#define MFMA(a, b, c) __builtin_amdgcn_mfma_f32_16x16x32_bf16(a, b, c, 0, 0, 0)

static __device__ inline u16 f2b(float f) {
    unsigned int u = __float_as_uint(f);
    unsigned int r = (u + 0x7fffu + ((u >> 16) & 1u)) >> 16;
    return (u16)r;
}
static __device__ inline float b2f(u16 u) {
    return __uint_as_float(((unsigned int)u) << 16);
}
static __device__ inline f32x4 b4x(bf4 v) {
    f32x4 r;
    r[0] = b2f((u16)v[0]); r[1] = b2f((u16)v[1]);
    r[2] = b2f((u16)v[2]); r[3] = b2f((u16)v[3]);
    return r;
}
static __device__ inline float fast_tanh(float x) {
    float e = __expf(2.f * x);
    return 1.f - 2.f / (e + 1.f);
}
static __device__ inline float fast_sigmoid(float x) {
    return 1.f / (1.f + __expf(-x));
}

// ---------------------------------------------------------------------------
// k_conv: f32 -> bf16 conversion pre-pass (7 weight arrays + x).
// ---------------------------------------------------------------------------
__global__ __launch_bounds__(256) void k_conv(
    const float* __restrict__ W1w, const float* __restrict__ U1w,
    const float* __restrict__ W2w, const float* __restrict__ U2w,
    const float* __restrict__ o1w, const float* __restrict__ o2w,
    const float* __restrict__ gw,  const float* __restrict__ x,
    u16* W1bf, u16* U1bf, u16* W2bf, u16* U2bf,
    u16* o1bf, u16* o2bf, u16* gbf, u16* xbf)
{
    const int a = blockIdx.y;
    const float* src; u16* dst; int n;
    switch (a) {
        case 0: src = W1w; dst = W1bf; n = 16384;   break;
        case 1: src = U1w; dst = U1bf; n = 65536;   break;
        case 2: src = W2w; dst = W2bf; n = 65536;   break;
        case 3: src = U2w; dst = U2bf; n = 65536;   break;
        case 4: src = o1w; dst = o1bf; n = 16384;   break;
        case 5: src = o2w; dst = o2bf; n = 16384;   break;
        case 6: src = gw;  dst = gbf;  n = 131072;  break;
        default: src = x;  dst = xbf;  n = 8388608; break;
    }
    const int i = (blockIdx.x * 256 + threadIdx.x) * 4;
    if (i < n) {
        f32x4 v = *(const f32x4*)(src + i);
        bf4 o;
        o[0] = (short)f2b(v[0]); o[1] = (short)f2b(v[1]);
        o[2] = (short)f2b(v[2]); o[3] = (short)f2b(v[3]);
        *(bf4*)(dst + i) = o;
    }
}

// ---------------------------------------------------------------------------
// h1 role: blocks 0-15. Chunk c. 8 waves, 2 n-chains each. bf16 x,
// prefetched one step ahead.
// ---------------------------------------------------------------------------
__device__ void h1_role(
    const u16* __restrict__ xbf, const u16* __restrict__ W1,
    const u16* __restrict__ U1, const float* __restrict__ W1b,
    const float* __restrict__ U1b, u16* __restrict__ H1,
    u16* __restrict__ h1state, int c, u16 (*buf)[H_ + 8])
{
    const int g = blockIdx.x;
    const int tid = threadIdx.x;
    const int w = tid >> 6, lane = tid & 63;
    const int col = lane & 15, quad = lane >> 4;
    const int t0 = c * Tc_;

    bf8 u1f[2][8], w1f[2][2];
    float bias[2];
#pragma unroll
    for (int i = 0; i < 2; ++i) {
        const int n = (w * 2 + i) * 16 + col;
#pragma unroll
        for (int kt = 0; kt < 8; ++kt)
            u1f[i][kt] = *(const bf8*)(U1 + (size_t)n * H_ + kt * 32 + quad * 8);
#pragma unroll
        for (int kt = 0; kt < 2; ++kt)
            w1f[i][kt] = *(const bf8*)(W1 + (size_t)n * D_ + kt * 32 + quad * 8);
        bias[i] = W1b[n] + U1b[n];
    }

    if (c == 0) {
        for (int idx = tid; idx < 16 * (H_ + 8); idx += 512)
            ((u16*)buf)[idx] = 0;
    } else {
        const int m = tid >> 5, hb = (tid & 31) * 8;
#pragma unroll
        for (int j = 0; j < 8; ++j)
            buf[m][hb + j] = h1state[(size_t)(g * 16 + m) * H_ + hb + j];
    }
    __syncthreads();

    const u16* xrow = xbf + (size_t)(g * 16 + col) * T_ * D_ + quad * 8;
    bf8 xa0 = *(const bf8*)(xrow + (size_t)t0 * D_);
    bf8 xa1 = *(const bf8*)(xrow + (size_t)t0 * D_ + 32);

#pragma unroll 1
    for (int tt = 0; tt < Tc_; ++tt) {
        const int tn = t0 + (tt + 1 < Tc_ ? tt + 1 : tt);
        bf8 xn0 = *(const bf8*)(xrow + (size_t)tn * D_);
        bf8 xn1 = *(const bf8*)(xrow + (size_t)tn * D_ + 32);

        bf8 haf[8];
#pragma unroll
        for (int kt = 0; kt < 8; ++kt)
            haf[kt] = *(const bf8*)&buf[col][kt * 32 + quad * 8];
        __syncthreads();  // reads done before overwrite

        f32x4 acc[2];
#pragma unroll
        for (int i = 0; i < 2; ++i) {
            acc[i][0] = bias[i]; acc[i][1] = bias[i];
            acc[i][2] = bias[i]; acc[i][3] = bias[i];
        }
#pragma unroll
        for (int kt = 0; kt < 8; ++kt)
#pragma unroll
            for (int i = 0; i < 2; ++i)
                acc[i] = MFMA(haf[kt], u1f[i][kt], acc[i]);
#pragma unroll
        for (int i = 0; i < 2; ++i) {
            acc[i] = MFMA(xa0, w1f[i][0], acc[i]);
            acc[i] = MFMA(xa1, w1f[i][1], acc[i]);
        }

#pragma unroll
        for (int i = 0; i < 2; ++i) {
            const int n = (w * 2 + i) * 16 + col;
#pragma unroll
            for (int r = 0; r < 4; ++r)
                buf[quad * 4 + r][n] = f2b(fast_tanh(acc[i][r]));
        }
        __syncthreads();
        {
            const int m = tid >> 5, hb = (tid & 31) * 8;
            bf8 v0 = *(const bf8*)&buf[m][hb];
            u16* dst = H1 + ((size_t)tt * 256 + g * 16 + m) * H_ + hb;
            *(bf8*)dst = v0;
        }
        xa0 = xn0; xa1 = xn1;
    }
    __syncthreads();
    {
        const int m = tid >> 5, hb = (tid & 31) * 8;
#pragma unroll
        for (int j = 0; j < 8; ++j)
            h1state[(size_t)(g * 16 + m) * H_ + hb + j] = buf[m][hb + j];
    }
}

// ---------------------------------------------------------------------------
// h2 role: blocks 16-47 (32 blocks x 8 batches). Single fused MFMA region
// per step: iteration tt computes preact(tt) AND gate/out(tt-1) from ONE
// A-fragment read of h2(tt-1). Epilogue iteration tt==Tc does gate/out(Tc-1).
// c-buffers are bf16 in half-fragment layout: only lanes 0-31 (quad<2,
// C rows 0-7 = this block's 8 batches) carry data; rows 8-15 ride as zeros.
// ---------------------------------------------------------------------------
__device__ void h2_role(
    const u16* __restrict__ U2, const u16* __restrict__ gw,
    const u16* __restrict__ o2w,
    const u16* __restrict__ W2c, const u16* __restrict__ G1c,
    const u16* __restrict__ O1c,
    float* __restrict__ out, float* __restrict__ h2state,
    float* __restrict__ ustate, int ch, u16 (*buf)[H_ + 8])
{
    const int g8 = blockIdx.x - 16;         // 0..31, batches [8*g8, 8*g8+8)
    const int tid = threadIdx.x;
    const int w = tid >> 6, lane = tid & 63;
    const int col = lane & 15, quad = lane >> 4;
    const int lane32 = lane & 31;
    const bool low = (quad < 2);            // C rows 0-7 = valid batches
    const int t0 = ch * Tc_;

    // weight fragments: each wave w owns U2 n-tiles {2w,2w+1}, g2 tiles
    // {2w,2w+1}; waves 0-3 additionally own o2 d-tile w.
    bf8 u2f[2][8], g2f[2][8], o2f[8];
#pragma unroll
    for (int i = 0; i < 2; ++i) {
        const int n = (w * 2 + i) * 16 + col;
#pragma unroll
        for (int kt = 0; kt < 8; ++kt) {
            u2f[i][kt] = *(const bf8*)(U2 + (size_t)n * H_ + kt * 32 + quad * 8);
            g2f[i][kt] = *(const bf8*)(gw + (size_t)n * (2 * H_) + H_ + kt * 32 + quad * 8);
        }
    }
    if (w < 4) {
#pragma unroll
        for (int kt = 0; kt < 8; ++kt)
            o2f[kt] = *(const bf8*)(o2w + (size_t)(w * 16 + col) * H_ + kt * 32 + quad * 8);
    }

    // states (f32, fragment order, lanes 0-31 only)
    f32x4 h2p[2], uu[2];
#pragma unroll
    for (int i = 0; i < 2; ++i) {
        h2p[i][0]=0.f; h2p[i][1]=0.f; h2p[i][2]=0.f; h2p[i][3]=0.f;
        uu[i][0]=1.f;  uu[i][1]=1.f;  uu[i][2]=1.f;  uu[i][3]=1.f;
    }
    if (ch > 0 && low) {
#pragma unroll
        for (int i = 0; i < 2; ++i) {
            size_t idx = (((size_t)g8 * 16 + (w * 2 + i)) * 32 + lane32) * 4;
            h2p[i] = *(const f32x4*)(h2state + idx);
            uu[i]  = *(const f32x4*)(ustate + idx);
        }
    }

    // zero h2buf (rows 8-15 stay zero forever), then seed rows 0-7
    for (int idx = tid; idx < 16 * (H_ + 8); idx += 512)
        ((u16*)buf)[idx] = 0;
    __syncthreads();
    if (low) {
#pragma unroll
        for (int i = 0; i < 2; ++i) {
            const int n = (w * 2 + i) * 16 + col;
#pragma unroll
            for (int r = 0; r < 4; ++r)
                buf[quad * 4 + r][n] = f2b(h2p[i][r]);
        }
    }
    __syncthreads();

    // prefetch W2c(0); G1c/O1c prefetched inside loop (used at tt+1)
    bf4 w2n[2], g1n[2], o1n;
    if (low) {
#pragma unroll
        for (int i = 0; i < 2; ++i)
            w2n[i] = *(const bf4*)(W2c +
                ((((size_t)g8 * Tc_) * 16 + (w * 2 + i)) * 32 + lane32) * 4);
    }

#pragma unroll 1
    for (int tt = 0; tt <= Tc_; ++tt) {
        // A-fragments of h2(tt-1)
        bf8 h2af[8];
#pragma unroll
        for (int kt = 0; kt < 8; ++kt)
            h2af[kt] = *(const bf8*)&buf[col][kt * 32 + quad * 8];
        __syncthreads();  // all reads done before this iteration's scatter

        f32x4 accU[2], accG[2], accO;
#pragma unroll
        for (int i = 0; i < 2; ++i) {
            accU[i][0]=0.f; accU[i][1]=0.f; accU[i][2]=0.f; accU[i][3]=0.f;
            accG[i][0]=0.f; accG[i][1]=0.f; accG[i][2]=0.f; accG[i][3]=0.f;
        }
        accO[0]=0.f; accO[1]=0.f; accO[2]=0.f; accO[3]=0.f;

        if (tt < Tc_ && low) {
#pragma unroll
            for (int i = 0; i < 2; ++i) accU[i] = b4x(w2n[i]);
        }
        if (tt >= 1 && low) {
#pragma unroll
            for (int i = 0; i < 2; ++i) accG[i] = b4x(g1n[i]);
            if (w < 4) accO = b4x(o1n);
        }
        // prefetches for next iteration
        if (tt < Tc_ && low) {
            const int tpf = (tt + 1 < Tc_) ? tt + 1 : Tc_ - 1;
#pragma unroll
            for (int i = 0; i < 2; ++i) {
                w2n[i] = *(const bf4*)(W2c +
                    ((((size_t)g8 * Tc_ + tpf) * 16 + (w * 2 + i)) * 32 + lane32) * 4);
                g1n[i] = *(const bf4*)(G1c +
                    ((((size_t)g8 * Tc_ + tt) * 16 + (w * 2 + i)) * 32 + lane32) * 4);
            }
            if (w < 4)
                o1n = *(const bf4*)(O1c +
                    ((((size_t)g8 * Tc_ + tt) * 4 + w) * 32 + lane32) * 4);
        }

        // fused MFMA region: up to 5 independent chains, kt-outer
        if (tt == 0) {
#pragma unroll
            for (int kt = 0; kt < 8; ++kt)
#pragma unroll
                for (int i = 0; i < 2; ++i)
                    accU[i] = MFMA(h2af[kt], u2f[i][kt], accU[i]);
        } else if (tt < Tc_) {
            if (w < 4) {
#pragma unroll
                for (int kt = 0; kt < 8; ++kt) {
                    accO = MFMA(h2af[kt], o2f[kt], accO);
#pragma unroll
                    for (int i = 0; i < 2; ++i) {
                        accU[i] = MFMA(h2af[kt], u2f[i][kt], accU[i]);
                        accG[i] = MFMA(h2af[kt], g2f[i][kt], accG[i]);
                    }
                }
            } else {
#pragma unroll
                for (int kt = 0; kt < 8; ++kt)
#pragma unroll
                    for (int i = 0; i < 2; ++i) {
                        accU[i] = MFMA(h2af[kt], u2f[i][kt], accU[i]);
                        accG[i] = MFMA(h2af[kt], g2f[i][kt], accG[i]);
                    }
            }
        } else {
            if (w < 4) {
#pragma unroll
                for (int kt = 0; kt < 8; ++kt) {
                    accO = MFMA(h2af[kt], o2f[kt], accO);
#pragma unroll
                    for (int i = 0; i < 2; ++i)
                        accG[i] = MFMA(h2af[kt], g2f[i][kt], accG[i]);
                }
            } else {
#pragma unroll
                for (int kt = 0; kt < 8; ++kt)
#pragma unroll
                    for (int i = 0; i < 2; ++i)
                        accG[i] = MFMA(h2af[kt], g2f[i][kt], accG[i]);
            }
        }

        // gate/out(tt-1)
        if (tt >= 1) {
            if (w < 4 && low) {
                const int t = t0 + tt - 1;
#pragma unroll
                for (int r = 0; r < 4; ++r)
                    out[((size_t)(g8 * 8 + quad * 4 + r) * T_ + t) * D_ + w * 16 + col] =
                        accO[r];
            }
#pragma unroll
            for (int i = 0; i < 2; ++i)
#pragma unroll
                for (int r = 0; r < 4; ++r)
                    uu[i][r] = fast_sigmoid(accG[i][r]);
        }
        // blend -> h2(tt), scatter to LDS
        if (tt < Tc_) {
#pragma unroll
            for (int i = 0; i < 2; ++i)
#pragma unroll
                for (int r = 0; r < 4; ++r) {
                    float h2n = fast_tanh(accU[i][r]);
                    h2p[i][r] = uu[i][r] * h2n + (1.f - uu[i][r]) * h2p[i][r];
                }
            if (low) {
#pragma unroll
                for (int i = 0; i < 2; ++i) {
                    const int n = (w * 2 + i) * 16 + col;
#pragma unroll
                    for (int r = 0; r < 4; ++r)
                        buf[quad * 4 + r][n] = f2b(h2p[i][r]);
                }
            }
        }
        __syncthreads();  // h2buf = h2(tt) ready
    }
    // save states: h2p = h2(Tc-1), uu = u(Tc-1) (from epilogue)
    if (low) {
#pragma unroll
        for (int i = 0; i < 2; ++i) {
            size_t idx = (((size_t)g8 * 16 + (w * 2 + i)) * 32 + lane32) * 4;
            *(f32x4*)(h2state + idx) = h2p[i];
            *(f32x4*)(ustate + idx)  = uu[i];
        }
    }
}

// ---------------------------------------------------------------------------
// k_pipe, lag-2 software pipeline across dispatches:
//   blocks 0-15 : h1 of chunk c          (c < NC_)
//   blocks 16-47: h2 of chunk c-2        (c >= 2)
//   blocks 48+  : gemm of chunk c-1      (1 <= c <= NC_)
// ---------------------------------------------------------------------------
__global__ __launch_bounds__(512, 2) void k_pipe(
    const u16* __restrict__ xbf, const u16* __restrict__ W1,
    const u16* __restrict__ U1, const float* __restrict__ W1b,
    const float* __restrict__ U1b, u16* __restrict__ H1w,
    u16* __restrict__ h1state,
    const u16* __restrict__ U2, const u16* __restrict__ gwgt,
    const u16* __restrict__ o2w,
    const u16* __restrict__ W2cr, const u16* __restrict__ G1cr,
    const u16* __restrict__ O1cr,
    float* __restrict__ out, float* __restrict__ h2state,
    float* __restrict__ ustate,
    const u16* __restrict__ H1r, const u16* __restrict__ W2,
    const u16* __restrict__ o1w,
    const float* __restrict__ W2b, const float* __restrict__ U2b,
    const float* __restrict__ gbias, const float* __restrict__ o1b,
    const float* __restrict__ o2b,
    u16* __restrict__ W2cw, u16* __restrict__ G1cw, u16* __restrict__ O1cw,
    int c)
{
    __shared__ __align__(16) u16 buf[16][H_ + 8];
    if (blockIdx.x < 16) {
        if (c < NC_)
            h1_role(xbf, W1, U1, W1b, U1b, H1w, h1state, c, buf);
    } else if (blockIdx.x < 48) {
        if (c >= 2)
            h2_role(U2, gwgt, o2w, W2cr, G1cr, O1cr, out, h2state, ustate, c - 2, buf);
    } else {
        if (c >= 1 && c <= NC_) {
            const int gbk = blockIdx.x - 48;
            const int tid = threadIdx.x;
            const int w = tid >> 6, lane = tid & 63;
            const int col = lane & 15, quad = lane >> 4;
            const int Wv = gbk * 8 + w;
            const int NT = (Tc_ * 256 / 16) * 9;   // 9216 wave-tasks

            for (int task = Wv; task < NT; task += GEMMB_ * 8) {
                const int mt = task & 1023, ny = task >> 10;
                const int mrow = mt * 16;

                f32x4 acc[4];
#pragma unroll
                for (int i = 0; i < 4; ++i) { acc[i][0]=0.f; acc[i][1]=0.f; acc[i][2]=0.f; acc[i][3]=0.f; }

#pragma unroll
                for (int kt = 0; kt < 8; ++kt) {
                    const int k = kt * 32 + quad * 8;
                    bf8 af = *(const bf8*)(H1r + (size_t)(mrow + col) * H_ + k);
#pragma unroll
                    for (int i = 0; i < 4; ++i) {
                        const int n = ny * 64 + i * 16 + col;
                        const u16* bp;
                        if (n < 256)      bp = W2   + (size_t)n * H_ + k;
                        else if (n < 512) bp = gwgt + (size_t)(n - 256) * (2 * H_) + k;
                        else              bp = o1w  + (size_t)(n - 512) * H_ + k;
                        bf8 bfv = *(const bf8*)bp;
                        acc[i] = MFMA(af, bfv, acc[i]);
                    }
                }

                const int tt  = mrow >> 8;
                const int g16 = (mrow & 255) >> 4;
                const int g8  = g16 * 2 + (quad >> 1);     // 8-batch region
                const int sub = ((quad & 1) << 4) | col;   // 0..31
#pragma unroll
                for (int i = 0; i < 4; ++i) {
                    const int n = ny * 64 + i * 16 + col;
                    float bias;
                    if (n < 256)      bias = W2b[n] + U2b[n];
                    else if (n < 512) bias = gbias[n - 256];
                    else              bias = o1b[n - 512] + o2b[n - 512];
                    bf4 v;
#pragma unroll
                    for (int r = 0; r < 4; ++r) v[r] = (short)f2b(acc[i][r] + bias);
                    const int nt = ny * 4 + i;
                    u16* dst;
                    if (nt < 16)
                        dst = W2cw + ((((size_t)g8 * Tc_ + tt) * 16 + nt) * 32 + sub) * 4;
                    else if (nt < 32)
                        dst = G1cw + ((((size_t)g8 * Tc_ + tt) * 16 + (nt - 16)) * 32 + sub) * 4;
                    else
                        dst = O1cw + ((((size_t)g8 * Tc_ + tt) * 4 + (nt - 32)) * 32 + sub) * 4;
                    *(bf4*)dst = v;
                }
            }
        }
    }
}

// ---------------------------------------------------------------------------
extern "C" void kernel_launch(void* const* d_in, const int* in_sizes, int n_in,
                              void* d_out, int out_size, void* d_ws, size_t ws_size,
                              hipStream_t stream)
{
    const float* x   = (const float*)d_in[0];
    const float* W1w = (const float*)d_in[1];
    const float* W1b = (const float*)d_in[2];
    const float* U1w = (const float*)d_in[3];
    const float* U1b = (const float*)d_in[4];
    const float* W2w = (const float*)d_in[5];
    const float* W2b = (const float*)d_in[6];
    const float* U2w = (const float*)d_in[7];
    const float* U2b = (const float*)d_in[8];
    const float* o1w = (const float*)d_in[9];
    const float* o1b = (const float*)d_in[10];
    const float* o2w = (const float*)d_in[11];
    const float* o2b = (const float*)d_in[12];
    const float* gw  = (const float*)d_in[13];
    const float* gb  = (const float*)d_in[14];
    float* out = (float*)d_out;
    (void)in_sizes; (void)n_in; (void)out_size; (void)ws_size;

    char* p = (char*)d_ws;
    u16* W1bf = (u16*)p; p += 16384 * 2;
    u16* U1bf = (u16*)p; p += 65536 * 2;
    u16* W2bf = (u16*)p; p += 65536 * 2;
    u16* U2bf = (u16*)p; p += 65536 * 2;
    u16* o1bf = (u16*)p; p += 16384 * 2;
    u16* o2bf = (u16*)p; p += 16384 * 2;
    u16* gbf  = (u16*)p; p += 131072 * 2;
    u16* xbf  = (u16*)p; p += (size_t)8388608 * 2;
    u16* H1[2]; u16* W2c[2]; u16* G1c[2]; u16* O1c[2];
    for (int pa = 0; pa < 2; ++pa) {
        H1[pa]  = (u16*)p; p += (size_t)Tc_ * 131072;  // Tc*256*256 bf16
        W2c[pa] = (u16*)p; p += (size_t)Tc_ * 131072;  // 32*Tc*16*128 bf16
        G1c[pa] = (u16*)p; p += (size_t)Tc_ * 131072;
        O1c[pa] = (u16*)p; p += (size_t)Tc_ * 32768;   // 32*Tc*4*128 bf16
    }
    u16* h1s   = (u16*)p;  p += 131072;
    float* h2s = (float*)p; p += 262144;
    float* us  = (float*)p;

    k_conv<<<dim3(8192, 8), 256, 0, stream>>>(W1w, U1w, W2w, U2w, o1w, o2w, gw, x,
                                              W1bf, U1bf, W2bf, U2bf, o1bf, o2bf,
                                              gbf, xbf);

    // lag-2 pipeline: dispatch c = { h1(c), gemm(c-1), h2(c-2) }
    for (int c = 0; c <= NC_ + 1; ++c) {
        const int pw = c & 1;         // h1 writes chunk c
        const int pg = (c + 1) & 1;   // gemm: chunk c-1  (reads H1[pg], writes C[pg])
        const int ph = c & 1;         // h2: chunk c-2    (reads C[ph])
        k_pipe<<<48 + GEMMB_, 512, 0, stream>>>(
            xbf, W1bf, U1bf, W1b, U1b, H1[pw], h1s,
            U2bf, gbf, o2bf, W2c[ph], G1c[ph], O1c[ph],
            out, h2s, us,
            H1[pg], W2bf, o1bf, W2b, U2b, gb, o1b, o2b,
            W2c[pg], G1c[pg], O1c[pg], c);
    }
}

// Round 8
// 1361.659 us; speedup vs baseline: 1.2730x; 1.2730x over previous
//
#include <hip/hip_runtime.h>

typedef unsigned short u16;
using bf8   = __attribute__((ext_vector_type(8))) short;  // 8 bf16 (4 VGPRs)
using bf4   = __attribute__((ext_vector_type(4))) short;  // 4 bf16
using f32x4 = __attribute__((ext_vector_type(4))) float;

#define B_ 256
#define T_ 512
#define D_ 64
#define H_ 256
#define Tc_ 64
#define NC_ (T_ / Tc_)
#define GEMMB_ 192   // gemm role blocks; 32+192=224 <= 256 CUs

#define MFMA(a, b, c) __builtin_amdgcn_mfma_f32_16x16x32_bf16(a, b, c, 0, 0, 0)

static __device__ inline u16 f2b(float f) {
    unsigned int u = __float_as_uint(f);
    unsigned int r = (u + 0x7fffu + ((u >> 16) & 1u)) >> 16;
    return (u16)r;
}
static __device__ inline float b2f(u16 u) {
    return __uint_as_float(((unsigned int)u) << 16);
}
static __device__ inline f32x4 b4x(bf4 v) {
    f32x4 r;
    r[0] = b2f((u16)v[0]); r[1] = b2f((u16)v[1]);
    r[2] = b2f((u16)v[2]); r[3] = b2f((u16)v[3]);
    return r;
}
static __device__ inline float fast_tanh(float x) {
    float e = __expf(2.f * x);
    return 1.f - 2.f / (e + 1.f);
}
static __device__ inline float fast_sigmoid(float x) {
    return 1.f / (1.f + __expf(-x));
}

// ---------------------------------------------------------------------------
// k_conv: f32 -> bf16 conversion pre-pass (7 weight arrays + x).
// ---------------------------------------------------------------------------
__global__ __launch_bounds__(256) void k_conv(
    const float* __restrict__ W1w, const float* __restrict__ U1w,
    const float* __restrict__ W2w, const float* __restrict__ U2w,
    const float* __restrict__ o1w, const float* __restrict__ o2w,
    const float* __restrict__ gw,  const float* __restrict__ x,
    u16* W1bf, u16* U1bf, u16* W2bf, u16* U2bf,
    u16* o1bf, u16* o2bf, u16* gbf, u16* xbf)
{
    const int a = blockIdx.y;
    const float* src; u16* dst; int n;
    switch (a) {
        case 0: src = W1w; dst = W1bf; n = 16384;   break;
        case 1: src = U1w; dst = U1bf; n = 65536;   break;
        case 2: src = W2w; dst = W2bf; n = 65536;   break;
        case 3: src = U2w; dst = U2bf; n = 65536;   break;
        case 4: src = o1w; dst = o1bf; n = 16384;   break;
        case 5: src = o2w; dst = o2bf; n = 16384;   break;
        case 6: src = gw;  dst = gbf;  n = 131072;  break;
        default: src = x;  dst = xbf;  n = 8388608; break;
    }
    const int i = (blockIdx.x * 256 + threadIdx.x) * 4;
    if (i < n) {
        f32x4 v = *(const f32x4*)(src + i);
        bf4 o;
        o[0] = (short)f2b(v[0]); o[1] = (short)f2b(v[1]);
        o[2] = (short)f2b(v[2]); o[3] = (short)f2b(v[3]);
        *(bf4*)(dst + i) = o;
    }
}

// ---------------------------------------------------------------------------
// h1 role: blocks 0-15, 16 batches each. Double-buffered LDS, ONE barrier
// per step. H1 history stored register-direct (scattered u16).
// ---------------------------------------------------------------------------
__device__ void h1_role(
    const u16* __restrict__ xbf, const u16* __restrict__ W1,
    const u16* __restrict__ U1, const float* __restrict__ W1b,
    const float* __restrict__ U1b, u16* __restrict__ H1,
    u16* __restrict__ h1state, int c, u16 (*bufs)[16][H_ + 8])
{
    const int g = blockIdx.x;
    const int tid = threadIdx.x;
    const int w = tid >> 6, lane = tid & 63;
    const int col = lane & 15, quad = lane >> 4;
    const int t0 = c * Tc_;

    bf8 u1f[2][8], w1f[2][2];
    float bias[2];
#pragma unroll
    for (int i = 0; i < 2; ++i) {
        const int n = (w * 2 + i) * 16 + col;
#pragma unroll
        for (int kt = 0; kt < 8; ++kt)
            u1f[i][kt] = *(const bf8*)(U1 + (size_t)n * H_ + kt * 32 + quad * 8);
#pragma unroll
        for (int kt = 0; kt < 2; ++kt)
            w1f[i][kt] = *(const bf8*)(W1 + (size_t)n * D_ + kt * 32 + quad * 8);
        bias[i] = W1b[n] + U1b[n];
    }

    // seed bufs[1] with h1(-1)
    if (c == 0) {
        for (int idx = tid; idx < 16 * (H_ + 8); idx += 512)
            ((u16*)bufs[1])[idx] = 0;
    } else {
        const int m = tid >> 5, hb = (tid & 31) * 8;
#pragma unroll
        for (int j = 0; j < 8; ++j)
            bufs[1][m][hb + j] = h1state[(size_t)(g * 16 + m) * H_ + hb + j];
    }
    __syncthreads();

    const u16* xrow = xbf + (size_t)(g * 16 + col) * T_ * D_ + quad * 8;
    bf8 xa0 = *(const bf8*)(xrow + (size_t)t0 * D_);
    bf8 xa1 = *(const bf8*)(xrow + (size_t)t0 * D_ + 32);

#pragma unroll 1
    for (int tt = 0; tt < Tc_; ++tt) {
        const int tn = t0 + (tt + 1 < Tc_ ? tt + 1 : tt);
        bf8 xn0 = *(const bf8*)(xrow + (size_t)tn * D_);
        bf8 xn1 = *(const bf8*)(xrow + (size_t)tn * D_ + 32);
        const int rp = (tt + 1) & 1, wp = tt & 1;

        bf8 haf[8];
#pragma unroll
        for (int kt = 0; kt < 8; ++kt)
            haf[kt] = *(const bf8*)&bufs[rp][col][kt * 32 + quad * 8];

        f32x4 acc[2];
#pragma unroll
        for (int i = 0; i < 2; ++i) {
            acc[i][0] = bias[i]; acc[i][1] = bias[i];
            acc[i][2] = bias[i]; acc[i][3] = bias[i];
        }
#pragma unroll
        for (int kt = 0; kt < 8; ++kt)
#pragma unroll
            for (int i = 0; i < 2; ++i)
                acc[i] = MFMA(haf[kt], u1f[i][kt], acc[i]);
#pragma unroll
        for (int i = 0; i < 2; ++i) {
            acc[i] = MFMA(xa0, w1f[i][0], acc[i]);
            acc[i] = MFMA(xa1, w1f[i][1], acc[i]);
        }

        // tanh -> bf16 once; write LDS (other buffer) + global H1 (row-major)
#pragma unroll
        for (int i = 0; i < 2; ++i) {
            const int n = (w * 2 + i) * 16 + col;
#pragma unroll
            for (int r = 0; r < 4; ++r) {
                u16 hv = f2b(fast_tanh(acc[i][r]));
                bufs[wp][quad * 4 + r][n] = hv;
                H1[((size_t)tt * 256 + g * 16 + quad * 4 + r) * H_ + n] = hv;
            }
        }
        __syncthreads();
        xa0 = xn0; xa1 = xn1;
    }
    // h1(Tc-1) sits in bufs[1] (Tc even)
    {
        const int m = tid >> 5, hb = (tid & 31) * 8;
#pragma unroll
        for (int j = 0; j < 8; ++j)
            h1state[(size_t)(g * 16 + m) * H_ + hb + j] = bufs[1][m][hb + j];
    }
}

// ---------------------------------------------------------------------------
// h2 role: blocks 16-31, 16 batches each. Fused single MFMA region per step:
// iteration tt reads h2(tt-1) ONCE and computes preact(tt) [U2 chains] AND
// gate(tt-1) [g2 chains]. Double-buffered LDS -> one barrier/step. Writes
// H2 history (row-major, register-direct) for the lag-3 out-gemm.
// No o2/out work here (offloaded).
// ---------------------------------------------------------------------------
__device__ void h2_role(
    const u16* __restrict__ U2, const u16* __restrict__ gw,
    const u16* __restrict__ W2c, const u16* __restrict__ G1c,
    u16* __restrict__ H2, float* __restrict__ h2state,
    float* __restrict__ ustate, int ch, u16 (*bufs)[16][H_ + 8])
{
    const int g = blockIdx.x - 16;
    const int tid = threadIdx.x;
    const int w = tid >> 6, lane = tid & 63;
    const int col = lane & 15, quad = lane >> 4;

    bf8 u2f[2][8], g2f[2][8];
#pragma unroll
    for (int i = 0; i < 2; ++i) {
        const int n = (w * 2 + i) * 16 + col;
#pragma unroll
        for (int kt = 0; kt < 8; ++kt) {
            u2f[i][kt] = *(const bf8*)(U2 + (size_t)n * H_ + kt * 32 + quad * 8);
            g2f[i][kt] = *(const bf8*)(gw + (size_t)n * (2 * H_) + H_ + kt * 32 + quad * 8);
        }
    }

    f32x4 h2p[2], uu[2];
#pragma unroll
    for (int i = 0; i < 2; ++i) {
        h2p[i][0]=0.f; h2p[i][1]=0.f; h2p[i][2]=0.f; h2p[i][3]=0.f;
        uu[i][0]=1.f;  uu[i][1]=1.f;  uu[i][2]=1.f;  uu[i][3]=1.f;
    }
    if (ch > 0) {
#pragma unroll
        for (int i = 0; i < 2; ++i) {
            size_t idx = (((size_t)g * 16 + (w * 2 + i)) * 64 + lane) * 4;
            h2p[i] = *(const f32x4*)(h2state + idx);
            uu[i]  = *(const f32x4*)(ustate + idx);
        }
    }

    // seed bufs[1] with h2(-1) (full coverage: 4 quads x 4 r = 16 rows,
    // 8 waves x 2 tiles = 256 cols)
#pragma unroll
    for (int i = 0; i < 2; ++i) {
        const int n = (w * 2 + i) * 16 + col;
#pragma unroll
        for (int r = 0; r < 4; ++r)
            bufs[1][quad * 4 + r][n] = f2b(h2p[i][r]);
    }
    __syncthreads();

    bf4 w2n[2], g1n[2];
#pragma unroll
    for (int i = 0; i < 2; ++i)
        w2n[i] = *(const bf4*)(W2c +
            ((((size_t)g * Tc_) * 16 + (w * 2 + i)) * 64 + lane) * 4);

#pragma unroll 1
    for (int tt = 0; tt <= Tc_; ++tt) {
        const int rp = (tt + 1) & 1, wp = tt & 1;
        bf8 h2af[8];
#pragma unroll
        for (int kt = 0; kt < 8; ++kt)
            h2af[kt] = *(const bf8*)&bufs[rp][col][kt * 32 + quad * 8];

        f32x4 accU[2], accG[2];
#pragma unroll
        for (int i = 0; i < 2; ++i) {
            if (tt < Tc_) accU[i] = b4x(w2n[i]);
            else { accU[i][0]=0.f; accU[i][1]=0.f; accU[i][2]=0.f; accU[i][3]=0.f; }
            if (tt >= 1) accG[i] = b4x(g1n[i]);
            else { accG[i][0]=0.f; accG[i][1]=0.f; accG[i][2]=0.f; accG[i][3]=0.f; }
        }
        // prefetch next step's c-buf values
        if (tt < Tc_) {
            const int tpf = (tt + 1 < Tc_) ? tt + 1 : Tc_ - 1;
#pragma unroll
            for (int i = 0; i < 2; ++i) {
                w2n[i] = *(const bf4*)(W2c +
                    ((((size_t)g * Tc_ + tpf) * 16 + (w * 2 + i)) * 64 + lane) * 4);
                g1n[i] = *(const bf4*)(G1c +
                    ((((size_t)g * Tc_ + tt) * 16 + (w * 2 + i)) * 64 + lane) * 4);
            }
        }

        // fused MFMA region: 4 independent chains, kt-outer
        if (tt == 0) {
#pragma unroll
            for (int kt = 0; kt < 8; ++kt)
#pragma unroll
                for (int i = 0; i < 2; ++i)
                    accU[i] = MFMA(h2af[kt], u2f[i][kt], accU[i]);
        } else if (tt < Tc_) {
#pragma unroll
            for (int kt = 0; kt < 8; ++kt)
#pragma unroll
                for (int i = 0; i < 2; ++i) {
                    accU[i] = MFMA(h2af[kt], u2f[i][kt], accU[i]);
                    accG[i] = MFMA(h2af[kt], g2f[i][kt], accG[i]);
                }
        } else {
#pragma unroll
            for (int kt = 0; kt < 8; ++kt)
#pragma unroll
                for (int i = 0; i < 2; ++i)
                    accG[i] = MFMA(h2af[kt], g2f[i][kt], accG[i]);
        }

        if (tt >= 1) {
#pragma unroll
            for (int i = 0; i < 2; ++i)
#pragma unroll
                for (int r = 0; r < 4; ++r)
                    uu[i][r] = fast_sigmoid(accG[i][r]);   // u(tt-1)
        }
        if (tt < Tc_) {
#pragma unroll
            for (int i = 0; i < 2; ++i) {
                const int n = (w * 2 + i) * 16 + col;
#pragma unroll
                for (int r = 0; r < 4; ++r) {
                    float h2n = fast_tanh(accU[i][r]);
                    h2p[i][r] = uu[i][r] * h2n + (1.f - uu[i][r]) * h2p[i][r];
                    u16 hv = f2b(h2p[i][r]);
                    bufs[wp][quad * 4 + r][n] = hv;
                    H2[((size_t)tt * 256 + g * 16 + quad * 4 + r) * H_ + n] = hv;
                }
            }
        }
        __syncthreads();
    }
    // save states: h2p = h2(Tc-1), uu = u(Tc-1) (epilogue)
#pragma unroll
    for (int i = 0; i < 2; ++i) {
        size_t idx = (((size_t)g * 16 + (w * 2 + i)) * 64 + lane) * 4;
        *(f32x4*)(h2state + idx) = h2p[i];
        *(f32x4*)(ustate + idx)  = uu[i];
    }
}

// ---------------------------------------------------------------------------
// k_pipe, lag-3 software pipeline across dispatches:
//   blocks 0-15 : h1 of chunk c            (c < NC_)
//   blocks 16-31: h2 of chunk c-2          (2 <= c <= NC_+1)
//   blocks 32+  : gemm1 of chunk c-1 (W2c,G1c from H1)   (1 <= c <= NC_)
//                 gemm2 of chunk c-3 (out = [o1 o2]@[H1;H2])  (3 <= c <= NC_+2)
// ---------------------------------------------------------------------------
__global__ __launch_bounds__(512, 2) void k_pipe(
    const u16* __restrict__ xbf, const u16* __restrict__ W1,
    const u16* __restrict__ U1, const float* __restrict__ W1b,
    const float* __restrict__ U1b, u16* __restrict__ H1w,
    u16* __restrict__ h1state,
    const u16* __restrict__ U2, const u16* __restrict__ gwgt,
    const u16* __restrict__ W2cr, const u16* __restrict__ G1cr,
    u16* __restrict__ H2w, float* __restrict__ h2state, float* __restrict__ ustate,
    const u16* __restrict__ H1r1, const u16* __restrict__ W2,
    u16* __restrict__ W2cw, u16* __restrict__ G1cw,
    const float* __restrict__ W2b, const float* __restrict__ U2b,
    const float* __restrict__ gbias,
    const u16* __restrict__ H1r2, const u16* __restrict__ H2r,
    const u16* __restrict__ o1w, const u16* __restrict__ o2w,
    const float* __restrict__ o1b, const float* __restrict__ o2b,
    float* __restrict__ out, int c)
{
    __shared__ __align__(16) u16 bufs[2][16][H_ + 8];
    if (blockIdx.x < 16) {
        if (c < NC_)
            h1_role(xbf, W1, U1, W1b, U1b, H1w, h1state, c, bufs);
    } else if (blockIdx.x < 32) {
        if (c >= 2 && c <= NC_ + 1)
            h2_role(U2, gwgt, W2cr, G1cr, H2w, h2state, ustate, c - 2, bufs);
    } else {
        if (c < 1 || c > NC_ + 2) return;
        const int tid = threadIdx.x;
        const int w = tid >> 6, lane = tid & 63;
        const int col = lane & 15, quad = lane >> 4;
        const int Wv = (blockIdx.x - 32) * 8 + w;
        const int NT = 8192 + 1024;

        for (int task = Wv; task < NT; task += GEMMB_ * 8) {
            if (task < 8192) {
                // ---- gemm1: W2c/G1c for chunk c-1 ----
                if (c > NC_) continue;
                const int mt = task & 1023, ny = task >> 10;  // ny 0..7
                const int mrow = mt * 16;
                f32x4 acc[4];
#pragma unroll
                for (int i = 0; i < 4; ++i) { acc[i][0]=0.f; acc[i][1]=0.f; acc[i][2]=0.f; acc[i][3]=0.f; }
#pragma unroll
                for (int kt = 0; kt < 8; ++kt) {
                    const int k = kt * 32 + quad * 8;
                    bf8 af = *(const bf8*)(H1r1 + (size_t)(mrow + col) * H_ + k);
#pragma unroll
                    for (int i = 0; i < 4; ++i) {
                        const int n = ny * 64 + i * 16 + col;
                        const u16* bp = (n < 256) ? (W2 + (size_t)n * H_ + k)
                                                  : (gwgt + (size_t)(n - 256) * (2 * H_) + k);
                        bf8 bfv = *(const bf8*)bp;
                        acc[i] = MFMA(af, bfv, acc[i]);
                    }
                }
                const int tt = mrow >> 8;
                const int g  = (mrow & 255) >> 4;
#pragma unroll
                for (int i = 0; i < 4; ++i) {
                    const int n = ny * 64 + i * 16 + col;
                    const float bias = (n < 256) ? (W2b[n] + U2b[n]) : gbias[n - 256];
                    bf4 v;
#pragma unroll
                    for (int r = 0; r < 4; ++r) v[r] = (short)f2b(acc[i][r] + bias);
                    const int nt = ny * 4 + i;
                    u16* dst = (nt < 16)
                        ? W2cw + ((((size_t)g * Tc_ + tt) * 16 + nt) * 64 + lane) * 4
                        : G1cw + ((((size_t)g * Tc_ + tt) * 16 + (nt - 16)) * 64 + lane) * 4;
                    *(bf4*)dst = v;
                }
            } else {
                // ---- gemm2: out for chunk c-3, K=512 over [H1;H2] ----
                if (c < 3) continue;
                const int tk = task - 8192;          // 0..1023
                const int mrow = tk * 16;
                f32x4 acc[4];
#pragma unroll
                for (int i = 0; i < 4; ++i) { acc[i][0]=0.f; acc[i][1]=0.f; acc[i][2]=0.f; acc[i][3]=0.f; }
#pragma unroll
                for (int kt = 0; kt < 8; ++kt) {
                    const int k = kt * 32 + quad * 8;
                    bf8 af = *(const bf8*)(H1r2 + (size_t)(mrow + col) * H_ + k);
#pragma unroll
                    for (int i = 0; i < 4; ++i) {
                        bf8 bfv = *(const bf8*)(o1w + (size_t)(i * 16 + col) * H_ + k);
                        acc[i] = MFMA(af, bfv, acc[i]);
                    }
                }
#pragma unroll
                for (int kt = 0; kt < 8; ++kt) {
                    const int k = kt * 32 + quad * 8;
                    bf8 af = *(const bf8*)(H2r + (size_t)(mrow + col) * H_ + k);
#pragma unroll
                    for (int i = 0; i < 4; ++i) {
                        bf8 bfv = *(const bf8*)(o2w + (size_t)(i * 16 + col) * H_ + k);
                        acc[i] = MFMA(af, bfv, acc[i]);
                    }
                }
                const int tt = mrow >> 8;
                const int bb = mrow & 255;
                const int t  = (c - 3) * Tc_ + tt;
#pragma unroll
                for (int i = 0; i < 4; ++i) {
                    const int d = i * 16 + col;
                    const float bias = o1b[d] + o2b[d];
#pragma unroll
                    for (int r = 0; r < 4; ++r)
                        out[((size_t)(bb + quad * 4 + r) * T_ + t) * D_ + d] =
                            acc[i][r] + bias;
                }
            }
        }
    }
}

// ---------------------------------------------------------------------------
extern "C" void kernel_launch(void* const* d_in, const int* in_sizes, int n_in,
                              void* d_out, int out_size, void* d_ws, size_t ws_size,
                              hipStream_t stream)
{
    const float* x   = (const float*)d_in[0];
    const float* W1w = (const float*)d_in[1];
    const float* W1b = (const float*)d_in[2];
    const float* U1w = (const float*)d_in[3];
    const float* U1b = (const float*)d_in[4];
    const float* W2w = (const float*)d_in[5];
    const float* W2b = (const float*)d_in[6];
    const float* U2w = (const float*)d_in[7];
    const float* U2b = (const float*)d_in[8];
    const float* o1w = (const float*)d_in[9];
    const float* o1b = (const float*)d_in[10];
    const float* o2w = (const float*)d_in[11];
    const float* o2b = (const float*)d_in[12];
    const float* gw  = (const float*)d_in[13];
    const float* gb  = (const float*)d_in[14];
    float* out = (float*)d_out;
    (void)in_sizes; (void)n_in; (void)out_size; (void)ws_size;

    char* p = (char*)d_ws;
    u16* W1bf = (u16*)p; p += 16384 * 2;
    u16* U1bf = (u16*)p; p += 65536 * 2;
    u16* W2bf = (u16*)p; p += 65536 * 2;
    u16* U2bf = (u16*)p; p += 65536 * 2;
    u16* o1bf = (u16*)p; p += 16384 * 2;
    u16* o2bf = (u16*)p; p += 16384 * 2;
    u16* gbf  = (u16*)p; p += 131072 * 2;
    u16* xbf  = (u16*)p; p += (size_t)8388608 * 2;
    const size_t CH = (size_t)Tc_ * 256 * 256;   // elems per chunk buffer
    u16* H1[4];
    for (int i = 0; i < 4; ++i) { H1[i] = (u16*)p; p += CH * 2; }
    u16* W2c[2]; u16* G1c[2]; u16* H2[2];
    for (int i = 0; i < 2; ++i) { W2c[i] = (u16*)p; p += CH * 2; }
    for (int i = 0; i < 2; ++i) { G1c[i] = (u16*)p; p += CH * 2; }
    for (int i = 0; i < 2; ++i) { H2[i]  = (u16*)p; p += CH * 2; }
    u16* h1s   = (u16*)p;  p += 65536 * 2;
    float* h2s = (float*)p; p += 65536 * 4;
    float* us  = (float*)p;

    k_conv<<<dim3(8192, 8), 256, 0, stream>>>(W1w, U1w, W2w, U2w, o1w, o2w, gw, x,
                                              W1bf, U1bf, W2bf, U2bf, o1bf, o2bf,
                                              gbf, xbf);

    // lag-3 pipeline: dispatch c = { h1(c), gemm1(c-1), h2(c-2), gemm2(c-3) }
    for (int c = 0; c <= NC_ + 2; ++c) {
        k_pipe<<<32 + GEMMB_, 512, 0, stream>>>(
            xbf, W1bf, U1bf, W1b, U1b, H1[c & 3], h1s,
            U2bf, gbf, W2c[c & 1], G1c[c & 1],
            H2[c & 1], h2s, us,
            H1[(c - 1) & 3], W2bf, W2c[(c - 1) & 1], G1c[(c - 1) & 1],
            W2b, U2b, gb,
            H1[(c - 3) & 3], H2[(c - 3) & 1], o1bf, o2bf, o1b, o2b,
            out, c);
    }
}